// Round 1
// baseline (1908.736 us; speedup 1.0000x reference)
//
#include <hip/hip_runtime.h>
#include <math.h>

#define N_NODES 50000
#define N_EDGES 400000
#define F_DIM   128
#define N_RBF   20

// ---------------------------------------------------------------------------
// Kernel A: phi_table[t][0..383] = silu(emb_table[t] @ w_phi1 + b_phi1) @ w_phi2 + b_phi2
// Only 100 atom types -> the whole per-edge MLP collapses to a 150 KB table.
// ---------------------------------------------------------------------------
__global__ void phi_table_kernel(const float* __restrict__ emb_table,
                                 const float* __restrict__ w_phi1,
                                 const float* __restrict__ b_phi1,
                                 const float* __restrict__ w_phi2,
                                 const float* __restrict__ b_phi2,
                                 float* __restrict__ phi_table) {
    __shared__ float emb_s[F_DIM];
    __shared__ float h_s[F_DIM];
    const int t = blockIdx.x;
    const int f = threadIdx.x;
    emb_s[f] = emb_table[t * F_DIM + f];
    __syncthreads();
    float acc = b_phi1[f];
#pragma unroll 8
    for (int k = 0; k < F_DIM; ++k)
        acc = fmaf(emb_s[k], w_phi1[k * F_DIM + f], acc);
    h_s[f] = acc / (1.0f + expf(-acc));   // silu
    __syncthreads();
#pragma unroll
    for (int c = 0; c < 3; ++c) {
        const int o = f + c * F_DIM;
        float a2 = b_phi2[o];
#pragma unroll 8
        for (int k = 0; k < F_DIM; ++k)
            a2 = fmaf(h_s[k], w_phi2[k * (3 * F_DIM) + o], a2);
        phi_table[t * (3 * F_DIM) + o] = a2;
    }
}

// ---------------------------------------------------------------------------
// Kernel B1: out_emb[i][f] = emb_table[z[i]][f]   (the "emb +" part)
// ---------------------------------------------------------------------------
__global__ void init_emb_kernel(const float* __restrict__ emb_table,
                                const int* __restrict__ z,
                                float* __restrict__ out_emb) {
    const int idx = blockIdx.x * blockDim.x + threadIdx.x;
    if (idx >= N_NODES * F_DIM) return;
    const int i = idx >> 7;
    const int f = idx & 127;
    out_emb[idx] = emb_table[z[i] * F_DIM + f];
}

// ---------------------------------------------------------------------------
// Kernel B2: out_eq = eq  (the "eq +" part), float4-vectorized copy
// ---------------------------------------------------------------------------
__global__ void copy_eq_kernel(const float4* __restrict__ eq,
                               float4* __restrict__ out_eq) {
    const int n4 = N_NODES * F_DIM * 3 / 4;   // 4.8M
    const int idx = blockIdx.x * blockDim.x + threadIdx.x;
    if (idx < n4) out_eq[idx] = eq[idx];
}

// ---------------------------------------------------------------------------
// Kernel C: per-edge message + scatter-add.
// blockDim=256 = two 128-thread f-groups; each group owns one edge.
// rbf computed by lanes 0..19 of each wave, broadcast via __shfl.
// ---------------------------------------------------------------------------
__global__ void edge_kernel(const float* __restrict__ pos,
                            const float* __restrict__ eq,
                            const float* __restrict__ phi_table,
                            const float* __restrict__ w_rbf,
                            const float* __restrict__ b_rbf,
                            const int* __restrict__ z,
                            const int* __restrict__ esrc,
                            const int* __restrict__ edst,
                            float* __restrict__ out_emb,
                            float* __restrict__ out_eq) {
    const int tid = threadIdx.x;
    const int grp = tid >> 7;          // 0 or 1
    const int f   = tid & 127;
    const int e   = blockIdx.x * 2 + grp;
    if (e >= N_EDGES) return;

    const int j = esrc[e];             // source (neighbour)
    const int i = edst[e];             // destination (receiver)

    // rel = pos[i] - pos[j]  (uniform per group -> broadcast loads)
    const float px = pos[3 * i + 0] - pos[3 * j + 0];
    const float py = pos[3 * i + 1] - pos[3 * j + 1];
    const float pz = pos[3 * i + 2] - pos[3 * j + 2];
    const float dist  = sqrtf(px * px + py * py + pz * pz);
    const float inv_d = 1.0f / dist;
    const float a     = 0.6283185307179586f * dist;   // pi * dist / CUTOFF

    // rbf[n] = sin((n+1)*pi*d/5)/d  -- lanes 0..19 compute, shfl-broadcast below
    const int lane = tid & 63;
    float s_rbf = 0.0f;
    if (lane < N_RBF) s_rbf = sinf((float)(lane + 1) * a) * inv_d;

    const int t = z[j];
    const float* pt = phi_table + t * (3 * F_DIM);
    const float phi1 = pt[f];
    const float phi2 = pt[f + F_DIM];
    const float phi3 = pt[f + 2 * F_DIM];

    float W1 = b_rbf[f];
    float W2 = b_rbf[f + F_DIM];
    float W3 = b_rbf[f + 2 * F_DIM];
#pragma unroll
    for (int n = 0; n < N_RBF; ++n) {
        const float r = __shfl(s_rbf, n);           // wave-wide broadcast
        const float* wr = w_rbf + n * (3 * F_DIM);  // 30 KB, L1-resident
        W1 = fmaf(r, wr[f], W1);
        W2 = fmaf(r, wr[f + F_DIM], W2);
        W3 = fmaf(r, wr[f + 2 * F_DIM], W3);
    }

    const float s1 = phi1 * W1;          // -> d_emb
    const float s2 = phi2 * W2;          // scales eq[src]
    const float s3 = phi3 * W3 * dist;   // scales rel (already * dist)

    atomicAdd(&out_emb[i * F_DIM + f], s1);

    const float* eqs = eq     + (size_t)j * (F_DIM * 3) + f * 3;
    float*       eqd = out_eq + (size_t)i * (F_DIM * 3) + f * 3;
    atomicAdd(&eqd[0], fmaf(eqs[0], s2, s3 * px));
    atomicAdd(&eqd[1], fmaf(eqs[1], s2, s3 * py));
    atomicAdd(&eqd[2], fmaf(eqs[2], s2, s3 * pz));
}

// ---------------------------------------------------------------------------
extern "C" void kernel_launch(void* const* d_in, const int* in_sizes, int n_in,
                              void* d_out, int out_size, void* d_ws, size_t ws_size,
                              hipStream_t stream) {
    const float* pos       = (const float*)d_in[0];
    const float* eq        = (const float*)d_in[1];
    const float* emb_table = (const float*)d_in[2];
    const float* w_phi1    = (const float*)d_in[3];
    const float* b_phi1    = (const float*)d_in[4];
    const float* w_phi2    = (const float*)d_in[5];
    const float* b_phi2    = (const float*)d_in[6];
    const float* w_rbf     = (const float*)d_in[7];
    const float* b_rbf     = (const float*)d_in[8];
    const int*   z         = (const int*)d_in[9];
    const int*   esrc      = (const int*)d_in[10];
    const int*   edst      = (const int*)d_in[11];

    float* out_emb = (float*)d_out;                               // [N, F]
    float* out_eq  = (float*)d_out + (size_t)N_NODES * F_DIM;     // [N, F, 3]
    float* phi_table = (float*)d_ws;                              // [100, 384]

    phi_table_kernel<<<100, F_DIM, 0, stream>>>(emb_table, w_phi1, b_phi1,
                                                w_phi2, b_phi2, phi_table);
    init_emb_kernel<<<(N_NODES * F_DIM + 255) / 256, 256, 0, stream>>>(
        emb_table, z, out_emb);
    copy_eq_kernel<<<(N_NODES * F_DIM * 3 / 4 + 255) / 256, 256, 0, stream>>>(
        (const float4*)eq, (float4*)out_eq);
    edge_kernel<<<N_EDGES / 2, 256, 0, stream>>>(pos, eq, phi_table,
                                                 w_rbf, b_rbf, z, esrc, edst,
                                                 out_emb, out_eq);
}

// Round 2
// 789.191 us; speedup vs baseline: 2.4186x; 2.4186x over previous
//
#include <hip/hip_runtime.h>
#include <math.h>

#define N_NODES 50000
#define N_EDGES 400000
#define F_DIM   128
#define N_RBF   20
#define SCAN_B  256
#define N_CHUNK ((N_NODES + SCAN_B - 1) / SCAN_B)   // 196 chunks of 256

// ---------------------------------------------------------------------------
// Kernel A: phi_table[t] = silu(emb_table[t] @ w_phi1 + b_phi1) @ w_phi2 + b_phi2
// 100 atom types -> whole per-edge MLP collapses to a 150 KB table.
// ---------------------------------------------------------------------------
__global__ void phi_table_kernel(const float* __restrict__ emb_table,
                                 const float* __restrict__ w_phi1,
                                 const float* __restrict__ b_phi1,
                                 const float* __restrict__ w_phi2,
                                 const float* __restrict__ b_phi2,
                                 float* __restrict__ phi_table) {
    __shared__ float emb_s[F_DIM];
    __shared__ float h_s[F_DIM];
    const int t = blockIdx.x;
    const int f = threadIdx.x;
    emb_s[f] = emb_table[t * F_DIM + f];
    __syncthreads();
    float acc = b_phi1[f];
#pragma unroll 8
    for (int k = 0; k < F_DIM; ++k)
        acc = fmaf(emb_s[k], w_phi1[k * F_DIM + f], acc);
    h_s[f] = acc / (1.0f + expf(-acc));   // silu
    __syncthreads();
#pragma unroll
    for (int c = 0; c < 3; ++c) {
        const int o = f + c * F_DIM;
        float a2 = b_phi2[o];
#pragma unroll 8
        for (int k = 0; k < F_DIM; ++k)
            a2 = fmaf(h_s[k], w_phi2[k * (3 * F_DIM) + o], a2);
        phi_table[t * (3 * F_DIM) + o] = a2;
    }
}

// ---------------------------------------------------------------------------
// CSR build: counting sort of edges by destination node.
// ---------------------------------------------------------------------------
__global__ void zero_counts_kernel(int* __restrict__ counts) {
    const int i = blockIdx.x * blockDim.x + threadIdx.x;
    if (i < N_NODES) counts[i] = 0;
}

__global__ void count_kernel(const int* __restrict__ edst, int* __restrict__ counts) {
    const int e = blockIdx.x * blockDim.x + threadIdx.x;
    if (e < N_EDGES) atomicAdd(&counts[edst[e]], 1);
}

// per-chunk exclusive scan (256 elems) + chunk sums
__global__ void scan_partial_kernel(const int* __restrict__ counts,
                                    int* __restrict__ partial,
                                    int* __restrict__ chunk_sums) {
    __shared__ int s[SCAN_B];
    const int tid = threadIdx.x;
    const int gid = blockIdx.x * SCAN_B + tid;
    const int v = (gid < N_NODES) ? counts[gid] : 0;
    s[tid] = v;
    __syncthreads();
    for (int d = 1; d < SCAN_B; d <<= 1) {
        const int t = (tid >= d) ? s[tid - d] : 0;
        __syncthreads();
        s[tid] += t;
        __syncthreads();
    }
    if (gid < N_NODES) partial[gid] = s[tid] - v;      // exclusive
    if (tid == SCAN_B - 1) chunk_sums[blockIdx.x] = s[tid];
}

// exclusive scan of the (<=256) chunk sums, single block
__global__ void scan_sums_kernel(int* __restrict__ chunk_sums,
                                 int* __restrict__ chunk_pref) {
    __shared__ int s[SCAN_B];
    const int tid = threadIdx.x;
    const int v = (tid < N_CHUNK) ? chunk_sums[tid] : 0;
    s[tid] = v;
    __syncthreads();
    for (int d = 1; d < SCAN_B; d <<= 1) {
        const int t = (tid >= d) ? s[tid - d] : 0;
        __syncthreads();
        s[tid] += t;
        __syncthreads();
    }
    if (tid < N_CHUNK) chunk_pref[tid] = s[tid] - v;   // exclusive
}

__global__ void finalize_offsets_kernel(const int* __restrict__ partial,
                                        const int* __restrict__ chunk_pref,
                                        int* __restrict__ offsets,
                                        int* __restrict__ cursor) {
    const int i = blockIdx.x * blockDim.x + threadIdx.x;
    if (i >= N_NODES) return;
    const int o = partial[i] + chunk_pref[i >> 8];
    offsets[i] = o;
    cursor[i]  = o;
}

__global__ void fill_kernel(const int* __restrict__ edst,
                            int* __restrict__ cursor,
                            int* __restrict__ edge_order) {
    const int e = blockIdx.x * blockDim.x + threadIdx.x;
    if (e >= N_EDGES) return;
    const int p = atomicAdd(&cursor[edst[e]], 1);
    edge_order[p] = e;
}

// ---------------------------------------------------------------------------
// Gather kernel: one 128-thread group per destination node. Registers
// accumulate d_emb / d_eq over the node's incoming edges; each output
// element is written exactly once (init fused in). No output atomics.
// ---------------------------------------------------------------------------
__global__ void gather_kernel(const float* __restrict__ pos,
                              const float* __restrict__ eq,
                              const float* __restrict__ emb_table,
                              const float* __restrict__ phi_table,
                              const float* __restrict__ w_rbf,
                              const float* __restrict__ b_rbf,
                              const int* __restrict__ z,
                              const int* __restrict__ esrc,
                              const int* __restrict__ offsets,
                              const int* __restrict__ counts,
                              const int* __restrict__ edge_order,
                              float* __restrict__ out_emb,
                              float* __restrict__ out_eq) {
    const int tid  = threadIdx.x;
    const int grp  = tid >> 7;                 // 0 or 1
    const int f    = tid & 127;
    const int lane = tid & 63;
    const int i    = blockIdx.x * 2 + grp;
    if (i >= N_NODES) return;

    const int start = offsets[i];
    const int cnt   = counts[i];
    const float pix = pos[3 * i + 0];
    const float piy = pos[3 * i + 1];
    const float piz = pos[3 * i + 2];

    const float br1 = b_rbf[f];
    const float br2 = b_rbf[f + F_DIM];
    const float br3 = b_rbf[f + 2 * F_DIM];

    float acc_e = 0.0f, a0 = 0.0f, a1 = 0.0f, a2 = 0.0f;

    for (int k = 0; k < cnt; ++k) {
        const int e = edge_order[start + k];
        const int j = esrc[e];

        const float px = pix - pos[3 * j + 0];
        const float py = piy - pos[3 * j + 1];
        const float pz = piz - pos[3 * j + 2];
        const float dist  = sqrtf(px * px + py * py + pz * pz);
        const float inv_d = 1.0f / dist;

        // rbf in lanes 0..19 of each wave, broadcast via shfl
        float s_rbf = 0.0f;
        if (lane < N_RBF)
            s_rbf = sinf((float)(lane + 1) * 0.6283185307179586f * dist) * inv_d;

        const int t = z[j];
        const float* pt = phi_table + t * (3 * F_DIM);
        const float phi1 = pt[f];
        const float phi2 = pt[f + F_DIM];
        const float phi3 = pt[f + 2 * F_DIM];

        float W1 = br1, W2 = br2, W3 = br3;
#pragma unroll
        for (int n = 0; n < N_RBF; ++n) {
            const float r = __shfl(s_rbf, n);
            const float* wr = w_rbf + n * (3 * F_DIM);   // 30 KB, L1-resident
            W1 = fmaf(r, wr[f], W1);
            W2 = fmaf(r, wr[f + F_DIM], W2);
            W3 = fmaf(r, wr[f + 2 * F_DIM], W3);
        }

        const float s2 = phi2 * W2;
        const float s3 = phi3 * W3 * dist;
        acc_e += phi1 * W1;

        const float* eqs = eq + ((size_t)j * F_DIM + f) * 3;
        a0 = fmaf(eqs[0], s2, fmaf(s3, px, a0));
        a1 = fmaf(eqs[1], s2, fmaf(s3, py, a1));
        a2 = fmaf(eqs[2], s2, fmaf(s3, pz, a2));
    }

    out_emb[(size_t)i * F_DIM + f] = emb_table[z[i] * F_DIM + f] + acc_e;

    const float* eqi = eq     + ((size_t)i * F_DIM + f) * 3;
    float*       eqd = out_eq + ((size_t)i * F_DIM + f) * 3;
    eqd[0] = eqi[0] + a0;
    eqd[1] = eqi[1] + a1;
    eqd[2] = eqi[2] + a2;
}

// ---------------------------------------------------------------------------
extern "C" void kernel_launch(void* const* d_in, const int* in_sizes, int n_in,
                              void* d_out, int out_size, void* d_ws, size_t ws_size,
                              hipStream_t stream) {
    const float* pos       = (const float*)d_in[0];
    const float* eq        = (const float*)d_in[1];
    const float* emb_table = (const float*)d_in[2];
    const float* w_phi1    = (const float*)d_in[3];
    const float* b_phi1    = (const float*)d_in[4];
    const float* w_phi2    = (const float*)d_in[5];
    const float* b_phi2    = (const float*)d_in[6];
    const float* w_rbf     = (const float*)d_in[7];
    const float* b_rbf     = (const float*)d_in[8];
    const int*   z         = (const int*)d_in[9];
    const int*   esrc      = (const int*)d_in[10];
    const int*   edst      = (const int*)d_in[11];

    float* out_emb = (float*)d_out;                               // [N, F]
    float* out_eq  = (float*)d_out + (size_t)N_NODES * F_DIM;     // [N, F, 3]

    // workspace layout
    char* ws = (char*)d_ws;
    float* phi_table  = (float*)ws;                 ws += 100 * 3 * F_DIM * sizeof(float);
    int*   counts     = (int*)ws;                   ws += N_NODES * sizeof(int);
    int*   partial    = (int*)ws;                   ws += N_NODES * sizeof(int);
    int*   offsets    = (int*)ws;                   ws += N_NODES * sizeof(int);
    int*   cursor     = (int*)ws;                   ws += N_NODES * sizeof(int);
    int*   chunk_sums = (int*)ws;                   ws += SCAN_B * sizeof(int);
    int*   chunk_pref = (int*)ws;                   ws += SCAN_B * sizeof(int);
    int*   edge_order = (int*)ws;                   ws += N_EDGES * sizeof(int);

    phi_table_kernel<<<100, F_DIM, 0, stream>>>(emb_table, w_phi1, b_phi1,
                                                w_phi2, b_phi2, phi_table);
    zero_counts_kernel<<<(N_NODES + 255) / 256, 256, 0, stream>>>(counts);
    count_kernel<<<(N_EDGES + 255) / 256, 256, 0, stream>>>(edst, counts);
    scan_partial_kernel<<<N_CHUNK, SCAN_B, 0, stream>>>(counts, partial, chunk_sums);
    scan_sums_kernel<<<1, SCAN_B, 0, stream>>>(chunk_sums, chunk_pref);
    finalize_offsets_kernel<<<(N_NODES + 255) / 256, 256, 0, stream>>>(
        partial, chunk_pref, offsets, cursor);
    fill_kernel<<<(N_EDGES + 255) / 256, 256, 0, stream>>>(edst, cursor, edge_order);
    gather_kernel<<<(N_NODES + 1) / 2, 256, 0, stream>>>(
        pos, eq, emb_table, phi_table, w_rbf, b_rbf, z, esrc,
        offsets, counts, edge_order, out_emb, out_eq);
}